// Round 1
// baseline (1356.414 us; speedup 1.0000x reference)
//
#include <hip/hip_runtime.h>
#include <hip/hip_bf16.h>

#define N_NODES 100000
#define N_EDGES 1600000
#define D_FEAT 64

// 16 threads per edge; each thread handles 4 consecutive features.
__global__ void spmm_atomic_kernel(const int* __restrict__ rows,
                                   const int* __restrict__ cols,
                                   const float* __restrict__ vals,
                                   const float* __restrict__ feats,
                                   float* __restrict__ out,
                                   int n_edges) {
    long long tid = (long long)blockIdx.x * blockDim.x + threadIdx.x;
    int e = (int)(tid >> 4);           // edge index
    if (e >= n_edges) return;
    int dgrp = (int)(tid & 15) << 2;   // feature offset: 0,4,...,60

    int r = rows[e];
    int c = cols[e];
    float v = vals[e];

    const float4 f = *reinterpret_cast<const float4*>(feats + (size_t)c * D_FEAT + dgrp);
    float* o = out + (size_t)r * D_FEAT + dgrp;

    atomicAdd(o + 0, v * f.x);
    atomicAdd(o + 1, v * f.y);
    atomicAdd(o + 2, v * f.z);
    atomicAdd(o + 3, v * f.w);
}

extern "C" void kernel_launch(void* const* d_in, const int* in_sizes, int n_in,
                              void* d_out, int out_size, void* d_ws, size_t ws_size,
                              hipStream_t stream) {
    const int* adj_indices = (const int*)d_in[0];   // [2, E] int32
    const float* adj_values = (const float*)d_in[1]; // [E] f32
    const float* feats = (const float*)d_in[2];      // [N, 64] f32
    float* out = (float*)d_out;                      // [N, 64] f32

    const int E = in_sizes[1];           // 1,600,000
    const int* rows = adj_indices;       // adj_indices[0]
    const int* cols = adj_indices + E;   // adj_indices[1]

    // Zero the output (harness poisons once; we must own initialization).
    hipMemsetAsync(d_out, 0, (size_t)out_size * sizeof(float), stream);

    const int threads = 256;
    long long total = (long long)E * 16;
    int blocks = (int)((total + threads - 1) / threads);
    spmm_atomic_kernel<<<blocks, threads, 0, stream>>>(rows, cols, adj_values,
                                                       feats, out, E);
}

// Round 2
// 300.765 us; speedup vs baseline: 4.5099x; 4.5099x over previous
//
#include <hip/hip_runtime.h>

#define NN 100000
#define NE 1600000
#define DF 64

// ---------------- CSR construction ----------------

__global__ void hist_kernel(const int* __restrict__ rows, int* __restrict__ counts, int E) {
    int stride = gridDim.x * blockDim.x;
    for (int i = blockIdx.x * blockDim.x + threadIdx.x; i < E; i += stride)
        atomicAdd(&counts[rows[i]], 1);
}

// scan1: per-block (1024-element chunk) sums
__global__ void scan1_kernel(const int* __restrict__ counts, int* __restrict__ bsum, int n) {
    __shared__ int s[256];
    int t = threadIdx.x;
    int base = blockIdx.x * 1024 + t * 4;
    int sum = 0;
#pragma unroll
    for (int j = 0; j < 4; ++j) { int idx = base + j; if (idx < n) sum += counts[idx]; }
    s[t] = sum; __syncthreads();
    for (int d = 128; d > 0; d >>= 1) { if (t < d) s[t] += s[t + d]; __syncthreads(); }
    if (t == 0) bsum[blockIdx.x] = s[0];
}

// scan2: exclusive scan of block sums (nb <= 128)
__global__ void scan2_kernel(const int* __restrict__ bsum, int* __restrict__ boff, int nb) {
    __shared__ int s[128];
    int t = threadIdx.x;
    int v = (t < nb) ? bsum[t] : 0;
    s[t] = v; __syncthreads();
    for (int d = 1; d < 128; d <<= 1) {
        int x = (t >= d) ? s[t - d] : 0;
        __syncthreads();
        s[t] += x;
        __syncthreads();
    }
    if (t < nb) boff[t] = s[t] - v;  // exclusive
}

// scan3: full exclusive scan -> offs[0..n-1]; also init cursor; offs[n]=E
__global__ void scan3_kernel(const int* __restrict__ counts, const int* __restrict__ boff,
                             int* __restrict__ offs, int* __restrict__ cur, int n, int E) {
    __shared__ int s[256];
    int t = threadIdx.x;
    int base = blockIdx.x * 1024 + t * 4;
    int c[4]; int sum = 0;
#pragma unroll
    for (int j = 0; j < 4; ++j) { int idx = base + j; c[j] = (idx < n) ? counts[idx] : 0; sum += c[j]; }
    s[t] = sum; __syncthreads();
    for (int d = 1; d < 256; d <<= 1) {
        int x = (t >= d) ? s[t - d] : 0;
        __syncthreads();
        s[t] += x;
        __syncthreads();
    }
    int excl = s[t] - sum + boff[blockIdx.x];
#pragma unroll
    for (int j = 0; j < 4; ++j) {
        int idx = base + j;
        if (idx < n) { offs[idx] = excl; cur[idx] = excl; excl += c[j]; }
    }
    if (blockIdx.x == 0 && t == 0) offs[n] = E;
}

__global__ void scatter_kernel(const int* __restrict__ rows, const int* __restrict__ cols,
                               const float* __restrict__ vals, int* __restrict__ cur,
                               int* __restrict__ scol, float* __restrict__ sval, int E) {
    int stride = gridDim.x * blockDim.x;
    for (int i = blockIdx.x * blockDim.x + threadIdx.x; i < E; i += stride) {
        int r = rows[i];
        int p = atomicAdd(&cur[r], 1);
        scol[p] = cols[i];
        sval[p] = vals[i];
    }
}

// ---------------- SpMM: one wave per row, lane = feature ----------------

__global__ void spmm_csr_kernel(const int* __restrict__ offs, const int* __restrict__ scol,
                                const float* __restrict__ sval, const float* __restrict__ feats,
                                float* __restrict__ out) {
    int wid = (blockIdx.x * blockDim.x + threadIdx.x) >> 6;  // one wave per row
    int lane = threadIdx.x & 63;
    if (wid >= NN) return;
    int beg = offs[wid], end = offs[wid + 1];
    float acc = 0.f;
    int i = beg;
    for (; i + 2 <= end; i += 2) {
        int c0 = scol[i], c1 = scol[i + 1];
        float v0 = sval[i], v1 = sval[i + 1];
        acc += v0 * feats[(size_t)c0 * DF + lane];
        acc += v1 * feats[(size_t)c1 * DF + lane];
    }
    if (i < end)
        acc += sval[i] * feats[(size_t)scol[i] * DF + lane];
    out[(size_t)wid * DF + lane] = acc;
}

// ---------------- launch ----------------

extern "C" void kernel_launch(void* const* d_in, const int* in_sizes, int n_in,
                              void* d_out, int out_size, void* d_ws, size_t ws_size,
                              hipStream_t stream) {
    const int* adj_indices = (const int*)d_in[0];    // [2, E] int32
    const float* adj_values = (const float*)d_in[1]; // [E] f32
    const float* feats = (const float*)d_in[2];      // [N, 64] f32
    float* out = (float*)d_out;

    const int E = in_sizes[1];
    const int N = NN;
    const int* rows = adj_indices;
    const int* cols = adj_indices + E;

    // workspace layout (int units, 64-int aligned)
    int* ws_i = (int*)d_ws;
    int* counts = ws_i + 0;        // N
    int* offs   = ws_i + 100032;   // N+1
    int* cur    = ws_i + 200064;   // N
    int* bsum   = ws_i + 300096;   // <=128
    int* boff   = ws_i + 300224;   // <=128
    int* scol   = ws_i + 300352;   // E
    float* sval = (float*)(ws_i + 300352 + NE); // E

    const int nb = (N + 1023) / 1024;  // 98

    hipMemsetAsync(counts, 0, (size_t)N * sizeof(int), stream);

    int gsBlocks = 2048;
    hist_kernel<<<gsBlocks, 256, 0, stream>>>(rows, counts, E);
    scan1_kernel<<<nb, 256, 0, stream>>>(counts, bsum, N);
    scan2_kernel<<<1, 128, 0, stream>>>(bsum, boff, nb);
    scan3_kernel<<<nb, 256, 0, stream>>>(counts, boff, offs, cur, N, E);
    scatter_kernel<<<gsBlocks, 256, 0, stream>>>(rows, cols, adj_values, cur, scol, sval, E);

    int spmmBlocks = (N * 64 + 255) / 256;  // 4 rows (waves) per block
    spmm_csr_kernel<<<spmmBlocks, 256, 0, stream>>>(offs, scol, sval, feats, out);
}

// Round 3
// 267.581 us; speedup vs baseline: 5.0692x; 1.1240x over previous
//
#include <hip/hip_runtime.h>

#define NN 100000
#define NE 1600000
#define DF 64

// ---------------- CSR construction ----------------

// 4 edges per thread, vectorized row load.
__global__ void hist_kernel(const int* __restrict__ rows, int* __restrict__ counts, int E4) {
    int t = blockIdx.x * blockDim.x + threadIdx.x;
    if (t >= E4) return;
    int4 r = reinterpret_cast<const int4*>(rows)[t];
    atomicAdd(&counts[r.x], 1);
    atomicAdd(&counts[r.y], 1);
    atomicAdd(&counts[r.z], 1);
    atomicAdd(&counts[r.w], 1);
}

// scan1: per-block (1024-element chunk) sums
__global__ void scan1_kernel(const int* __restrict__ counts, int* __restrict__ bsum, int n) {
    __shared__ int s[256];
    int t = threadIdx.x;
    int base = blockIdx.x * 1024 + t * 4;
    int sum = 0;
#pragma unroll
    for (int j = 0; j < 4; ++j) { int idx = base + j; if (idx < n) sum += counts[idx]; }
    s[t] = sum; __syncthreads();
    for (int d = 128; d > 0; d >>= 1) { if (t < d) s[t] += s[t + d]; __syncthreads(); }
    if (t == 0) bsum[blockIdx.x] = s[0];
}

// scan2: exclusive scan of block sums (nb <= 128)
__global__ void scan2_kernel(const int* __restrict__ bsum, int* __restrict__ boff, int nb) {
    __shared__ int s[128];
    int t = threadIdx.x;
    int v = (t < nb) ? bsum[t] : 0;
    s[t] = v; __syncthreads();
    for (int d = 1; d < 128; d <<= 1) {
        int x = (t >= d) ? s[t - d] : 0;
        __syncthreads();
        s[t] += x;
        __syncthreads();
    }
    if (t < nb) boff[t] = s[t] - v;  // exclusive
}

// scan3: full exclusive scan -> offs[0..n-1]; also init cursor; offs[n]=E
__global__ void scan3_kernel(const int* __restrict__ counts, const int* __restrict__ boff,
                             int* __restrict__ offs, int* __restrict__ cur, int n, int E) {
    __shared__ int s[256];
    int t = threadIdx.x;
    int base = blockIdx.x * 1024 + t * 4;
    int c[4]; int sum = 0;
#pragma unroll
    for (int j = 0; j < 4; ++j) { int idx = base + j; c[j] = (idx < n) ? counts[idx] : 0; sum += c[j]; }
    s[t] = sum; __syncthreads();
    for (int d = 1; d < 256; d <<= 1) {
        int x = (t >= d) ? s[t - d] : 0;
        __syncthreads();
        s[t] += x;
        __syncthreads();
    }
    int excl = s[t] - sum + boff[blockIdx.x];
#pragma unroll
    for (int j = 0; j < 4; ++j) {
        int idx = base + j;
        if (idx < n) { offs[idx] = excl; cur[idx] = excl; excl += c[j]; }
    }
    if (blockIdx.x == 0 && t == 0) offs[n] = E;
}

// 4 edges per thread; packed (col, val) single 8B store per edge.
__global__ void scatter_kernel(const int* __restrict__ rows, const int* __restrict__ cols,
                               const float* __restrict__ vals, int* __restrict__ cur,
                               int2* __restrict__ packed, int E4) {
    int t = blockIdx.x * blockDim.x + threadIdx.x;
    if (t >= E4) return;
    int4 r = reinterpret_cast<const int4*>(rows)[t];
    int4 c = reinterpret_cast<const int4*>(cols)[t];
    float4 v = reinterpret_cast<const float4*>(vals)[t];
    int p0 = atomicAdd(&cur[r.x], 1);
    int p1 = atomicAdd(&cur[r.y], 1);
    int p2 = atomicAdd(&cur[r.z], 1);
    int p3 = atomicAdd(&cur[r.w], 1);
    packed[p0] = make_int2(c.x, __float_as_int(v.x));
    packed[p1] = make_int2(c.y, __float_as_int(v.y));
    packed[p2] = make_int2(c.z, __float_as_int(v.z));
    packed[p3] = make_int2(c.w, __float_as_int(v.w));
}

// ---------------- SpMM: one wave per row; 4 edges x 16 feature-quads ----------------

__global__ void spmm_csr_kernel(const int* __restrict__ offs, const int2* __restrict__ packed,
                                const float* __restrict__ feats, float* __restrict__ out) {
    int wid = (blockIdx.x * blockDim.x + threadIdx.x) >> 6;  // one wave per row
    if (wid >= NN) return;
    int lane = threadIdx.x & 63;
    int grp = lane >> 4;   // which of 4 concurrent edges
    int fq = lane & 15;    // feature quad: floats [fq*4, fq*4+4)
    int beg = offs[wid], end = offs[wid + 1];

    float4 acc = make_float4(0.f, 0.f, 0.f, 0.f);
    for (int i = beg + grp; i < end; i += 4) {
        int2 cv = packed[i];
        float v = __int_as_float(cv.y);
        const float4 f = *reinterpret_cast<const float4*>(feats + (size_t)cv.x * DF + fq * 4);
        acc.x += v * f.x;
        acc.y += v * f.y;
        acc.z += v * f.z;
        acc.w += v * f.w;
    }
    // reduce the 4 edge-groups: butterfly over lane bits 16 and 32
#pragma unroll
    for (int m = 16; m <= 32; m <<= 1) {
        acc.x += __shfl_xor(acc.x, m, 64);
        acc.y += __shfl_xor(acc.y, m, 64);
        acc.z += __shfl_xor(acc.z, m, 64);
        acc.w += __shfl_xor(acc.w, m, 64);
    }
    if (grp == 0)
        *reinterpret_cast<float4*>(out + (size_t)wid * DF + fq * 4) = acc;
}

// ---------------- launch ----------------

extern "C" void kernel_launch(void* const* d_in, const int* in_sizes, int n_in,
                              void* d_out, int out_size, void* d_ws, size_t ws_size,
                              hipStream_t stream) {
    const int* adj_indices = (const int*)d_in[0];    // [2, E] int32
    const float* adj_values = (const float*)d_in[1]; // [E] f32
    const float* feats = (const float*)d_in[2];      // [N, 64] f32
    float* out = (float*)d_out;

    const int E = in_sizes[1];
    const int N = NN;
    const int* rows = adj_indices;
    const int* cols = adj_indices + E;

    // workspace layout (int units)
    int* ws_i = (int*)d_ws;
    int* counts = ws_i + 0;        // N
    int* offs   = ws_i + 100032;   // N+1
    int* cur    = ws_i + 200064;   // N
    int* bsum   = ws_i + 300096;   // <=128
    int* boff   = ws_i + 300224;   // <=128
    int2* packed = (int2*)(ws_i + 300352);  // E int2 (16B-aligned base)

    const int nb = (N + 1023) / 1024;  // 98
    const int E4 = E / 4;              // E divisible by 4

    hipMemsetAsync(counts, 0, (size_t)N * sizeof(int), stream);

    hist_kernel<<<(E4 + 255) / 256, 256, 0, stream>>>(rows, counts, E4);
    scan1_kernel<<<nb, 256, 0, stream>>>(counts, bsum, N);
    scan2_kernel<<<1, 128, 0, stream>>>(bsum, boff, nb);
    scan3_kernel<<<nb, 256, 0, stream>>>(counts, boff, offs, cur, N, E);
    scatter_kernel<<<(E4 + 255) / 256, 256, 0, stream>>>(rows, cols, adj_values, cur, packed, E4);

    int spmmBlocks = (N * 64 + 255) / 256;  // 4 rows (waves) per block
    spmm_csr_kernel<<<spmmBlocks, 256, 0, stream>>>(offs, packed, feats, out);
}